// Round 2
// baseline (992.609 us; speedup 1.0000x reference)
//
#include <hip/hip_runtime.h>

typedef __bf16 bf16x8 __attribute__((ext_vector_type(8)));
typedef float f32x4 __attribute__((ext_vector_type(4)));

#define DFEAT 128
#define HDIM 64
#define IDX_BITS 21
#define IDX_MASK ((1u << IDX_BITS) - 1)
#define EMPTY_SLOT 0xFFFFFFFFFFFFFFFFull

__device__ __forceinline__ float ssp(float x) {
    // shifted softplus: log(1+e^x) - log(2), numerically stable
    float ax = fabsf(x);
    return fmaxf(x, 0.0f) + log1pf(expf(-ax)) - 0.69314718055994531f;
}

// edge_index may arrive as int32 (harness contract) or int64 (reference dtype).
// Detect at runtime: int64 layout has all-zero odd dwords (values < 2^31).
__global__ void detect_idx_kernel(const unsigned int* __restrict__ p, int n_check,
                                  unsigned int* __restrict__ flag_any) {
    unsigned int acc = 0;
    for (int i = threadIdx.x; i < n_check; i += blockDim.x)
        acc |= p[2 * i + 1];
    if (acc) atomicOr(flag_any, 1u);
}

__device__ __forceinline__ int load_idx(const void* p, int is64, long long i) {
    if (is64) return (int)((const long long*)p)[i];
    return ((const int*)p)[i];
}

// Kernel A: per-edge MLP via split-bf16 MFMA (Ah*Wh + Al*Wh + Ah*Wl, ~2^-16 rel err);
// fused scatter-sum of mag & count per center. Wave = 16 edges x 64 hidden, K=128.
__global__ __launch_bounds__(256) void mlp_mag_kernel(
    const float* __restrict__ feats,
    const void* __restrict__ eidx,
    const float* __restrict__ w1,
    const float* __restrict__ b1,
    const float* __restrict__ w2,
    const float* __restrict__ b2,
    float* __restrict__ mag_raw,
    float* __restrict__ csum,
    float* __restrict__ ccnt,
    const unsigned int* __restrict__ flag_any,
    int E)
{
    const int is64 = (flag_any[0] == 0u) ? 1 : 0;
    const int lane = threadIdx.x & 63;
    const int r = lane & 15;   // A-row (edge) / B-col / C-col index
    const int g = lane >> 4;   // k-group
    const int wave = blockIdx.x * (blockDim.x >> 6) + (threadIdx.x >> 6);
    const int nwaves = gridDim.x * (blockDim.x >> 6);

    // B fragments: B[k][col], k = kt*32 + g*8 + i, col = nt*16 + r. hi/lo bf16 split.
    bf16x8 bH[4][4], bL[4][4];
#pragma unroll
    for (int kt = 0; kt < 4; ++kt)
#pragma unroll
        for (int nt = 0; nt < 4; ++nt)
#pragma unroll
            for (int i = 0; i < 8; ++i) {
                int k = kt * 32 + g * 8 + i;
                int col = nt * 16 + r;
                float w = w1[k * HDIM + col];
                __bf16 hi = (__bf16)w;
                bH[kt][nt][i] = hi;
                bL[kt][nt][i] = (__bf16)(w - (float)hi);
            }

    float b1v[4], w2v[4];
#pragma unroll
    for (int nt = 0; nt < 4; ++nt) {
        b1v[nt] = b1[nt * 16 + r];
        w2v[nt] = w2[nt * 16 + r];
    }
    const float b2v = b2[0];

    const int ntiles = (E + 15) >> 4;
    for (int tile = wave; tile < ntiles; tile += nwaves) {
        const int e0 = tile << 4;
        const int erow = e0 + r;

        // Load this lane's 32 feature floats (8 x float4), coalesced per row.
        float4 av[8];
        if (erow < E) {
            const float4* fp = (const float4*)(feats + (size_t)erow * DFEAT);
#pragma unroll
            for (int kt = 0; kt < 4; ++kt) {
                av[kt * 2 + 0] = fp[kt * 8 + g * 2 + 0];
                av[kt * 2 + 1] = fp[kt * 8 + g * 2 + 1];
            }
        } else {
#pragma unroll
            for (int q = 0; q < 8; ++q) av[q] = make_float4(0.f, 0.f, 0.f, 0.f);
        }

        f32x4 acc[4] = {{0.f,0.f,0.f,0.f},{0.f,0.f,0.f,0.f},{0.f,0.f,0.f,0.f},{0.f,0.f,0.f,0.f}};
#pragma unroll
        for (int kt = 0; kt < 4; ++kt) {
            bf16x8 aH, aL;
            const float* a8 = (const float*)&av[kt * 2];
#pragma unroll
            for (int i = 0; i < 8; ++i) {
                float x = a8[i];
                __bf16 hi = (__bf16)x;
                aH[i] = hi;
                aL[i] = (__bf16)(x - (float)hi);
            }
#pragma unroll
            for (int nt = 0; nt < 4; ++nt) {
                acc[nt] = __builtin_amdgcn_mfma_f32_16x16x32_bf16(aH, bH[kt][nt], acc[nt], 0, 0, 0);
                acc[nt] = __builtin_amdgcn_mfma_f32_16x16x32_bf16(aL, bH[kt][nt], acc[nt], 0, 0, 0);
                acc[nt] = __builtin_amdgcn_mfma_f32_16x16x32_bf16(aH, bL[kt][nt], acc[nt], 0, 0, 0);
            }
        }

        // Lane holds z[row = g*4+j][col = nt*16+r] = acc[nt][j].
        // mag-partial = sum_col ssp(z+b1)*w2; reduce across the 16 lanes of group g.
        float s[4];
#pragma unroll
        for (int j = 0; j < 4; ++j) {
            float t = 0.0f;
#pragma unroll
            for (int nt = 0; nt < 4; ++nt) {
                float z = acc[nt][j] + b1v[nt];
                t += ssp(z) * w2v[nt];
            }
            t += __shfl_xor(t, 1);
            t += __shfl_xor(t, 2);
            t += __shfl_xor(t, 4);
            t += __shfl_xor(t, 8);
            s[j] = t;
        }

        if (r < 4) {
            int e = e0 + g * 4 + r;
            if (e < E) {
                float mag = s[r] + b2v;
                mag_raw[e] = mag;
                int c = load_idx(eidx, is64, e);
                atomicAdd(&csum[c], mag);
                atomicAdd(&ccnt[c], 1.0f);
            }
        }
    }
}

// Kernel C: hash-join pairing (replaces argsort), debias, average, force scatter.
// The two directed copies of an undirected edge compute bitwise-identical keys
// (|(-v)/l| == |v/l| under IEEE), so an exact-match join reproduces the
// reference's sorted-pair grouping. Race-free: both partners walk the same
// probe sequence and slots never empty, so exactly one inserts.
__global__ __launch_bounds__(256) void pair_force_kernel(
    const float* __restrict__ vec,
    const float* __restrict__ len,
    const void* __restrict__ eidx,
    const float* __restrict__ mag_raw,
    const float* __restrict__ csum,
    const float* __restrict__ ccnt,
    unsigned long long* __restrict__ tab,
    float* __restrict__ out,
    const unsigned int* __restrict__ flag_any,
    int E, int hash_bits)
{
    int i = blockIdx.x * blockDim.x + threadIdx.x;
    if (i >= E) return;
    const int is64 = (flag_any[0] == 0u) ? 1 : 0;

    float l = len[i];
    float ux = vec[3 * i + 0] / l;
    float uy = vec[3 * i + 1] / l;
    float uz = vec[3 * i + 2] / l;
    float s3 = (fabsf(ux) + fabsf(uy)) + fabsf(uz);

    int ci_ = load_idx(eidx, is64, i);
    int ni_ = load_idx(eidx, is64, (long long)E + i);

    long long key = (long long)ci_ + (long long)ni_
                  + (long long)(1.0e10f * l)
                  + (long long)(1.0e10f * s3);

    unsigned long long entry = ((unsigned long long)key << IDX_BITS) | (unsigned)i;
    unsigned long long h = (unsigned long long)key * 0x9E3779B97F4A7C15ull;
    unsigned slot = (unsigned)(h >> (64 - hash_bits));
    const unsigned smask = (1u << hash_bits) - 1u;

    int j;
    while (true) {
        unsigned long long old = atomicCAS(&tab[slot], EMPTY_SLOT, entry);
        if (old == EMPTY_SLOT) return;  // first of the pair: partner finishes the job
        if ((old >> IDX_BITS) == (unsigned long long)key) {
            j = (int)(old & IDX_MASK);
            break;
        }
        slot = (slot + 1) & smask;
    }

    int cj_ = load_idx(eidx, is64, j);
    float mi = mag_raw[i] - csum[ci_] / fmaxf(ccnt[ci_], 1.0f);
    float mj = mag_raw[j] - csum[cj_] / fmaxf(ccnt[cj_], 1.0f);
    float avg = 0.5f * (mi + mj);

    atomicAdd(&out[ci_ * 3 + 0], avg * ux);
    atomicAdd(&out[ci_ * 3 + 1], avg * uy);
    atomicAdd(&out[ci_ * 3 + 2], avg * uz);

    float lj = len[j];
    float ujx = vec[3 * j + 0] / lj;
    float ujy = vec[3 * j + 1] / lj;
    float ujz = vec[3 * j + 2] / lj;
    atomicAdd(&out[cj_ * 3 + 0], avg * ujx);
    atomicAdd(&out[cj_ * 3 + 1], avg * ujy);
    atomicAdd(&out[cj_ * 3 + 2], avg * ujz);
}

extern "C" void kernel_launch(void* const* d_in, const int* in_sizes, int n_in,
                              void* d_out, int out_size, void* d_ws, size_t ws_size,
                              hipStream_t stream) {
    const float* feats = (const float*)d_in[0];
    const float* vec   = (const float*)d_in[1];
    const float* len   = (const float*)d_in[2];
    const void*  eidx  = d_in[3];
    const float* w1 = (const float*)d_in[4];
    const float* b1 = (const float*)d_in[5];
    const float* w2 = (const float*)d_in[6];
    const float* b2 = (const float*)d_in[7];
    float* out = (float*)d_out;

    const int E = in_sizes[0] / DFEAT;
    const int N = out_size / 3;

    // Workspace layout (256B aligned regions):
    //   mag_raw: E floats | csum: N floats | ccnt: N floats | flag: 256B | tab
    char* ws = (char*)d_ws;
    size_t off_mag  = 0;
    size_t off_csum = (off_mag + (size_t)E * 4 + 255) & ~(size_t)255;
    size_t off_ccnt = off_csum + (size_t)N * 4;
    size_t off_flag = (off_ccnt + (size_t)N * 4 + 255) & ~(size_t)255;
    size_t off_tab  = off_flag + 256;

    float* mag_raw = (float*)(ws + off_mag);
    float* csum    = (float*)(ws + off_csum);
    float* ccnt    = (float*)(ws + off_ccnt);
    unsigned int* flag_any = (unsigned int*)(ws + off_flag);

    int hash_bits = 22;
    while (hash_bits > 20 && off_tab + (8ull << hash_bits) > ws_size) --hash_bits;
    unsigned long long* tab = (unsigned long long*)(ws + off_tab);

    hipMemsetAsync(csum, 0, (size_t)2 * N * 4, stream);
    hipMemsetAsync(flag_any, 0, 256, stream);
    hipMemsetAsync(tab, 0xFF, (size_t)8 << hash_bits, stream);
    hipMemsetAsync(out, 0, (size_t)out_size * 4, stream);

    int n_check = E < 1024 ? E : 1024;
    detect_idx_kernel<<<1, 256, 0, stream>>>((const unsigned int*)eidx, n_check, flag_any);

    mlp_mag_kernel<<<2048, 256, 0, stream>>>(feats, eidx, w1, b1, w2, b2,
                                             mag_raw, csum, ccnt, flag_any, E);

    int blocks = (E + 255) / 256;
    pair_force_kernel<<<blocks, 256, 0, stream>>>(vec, len, eidx, mag_raw, csum, ccnt,
                                                  tab, out, flag_any, E, hash_bits);
}